// Round 5
// baseline (3412.938 us; speedup 1.0000x reference)
//
#include <hip/hip_runtime.h>
#include <math.h>

// Problem dims (fixed by reference)
#define SEQ   128
#define BATCH 64
#define HD    1024
#define NG    4096
#define TOUT  32
#define NE    65536    // BATCH*HD

typedef __attribute__((ext_vector_type(8))) short short8;
typedef __attribute__((ext_vector_type(4))) float f32x4;

#define MFMA16(a,b,c) __builtin_amdgcn_mfma_f32_16x16x32_bf16((a),(b),(c),0,0,0)

__device__ __forceinline__ ushort bf16_rne(float x) {
    union { float f; unsigned u; } v; v.f = x;
    unsigned r = v.u + 0x7FFF + ((v.u >> 16) & 1);
    return (ushort)(r >> 16);
}

// ---- device-coherent (agent-scope, L3-point) accesses: sc0|sc1, no fences ----
__device__ __forceinline__ unsigned long long cload64(const void* p) {
    return __hip_atomic_load((const unsigned long long*)p, __ATOMIC_RELAXED,
                             __HIP_MEMORY_SCOPE_AGENT);
}
__device__ __forceinline__ void cstore32(void* p, unsigned v) {
    __hip_atomic_store((unsigned*)p, v, __ATOMIC_RELAXED, __HIP_MEMORY_SCOPE_AGENT);
}
__device__ __forceinline__ void cstore64(void* p, unsigned long long v) {
    __hip_atomic_store((unsigned long long*)p, v, __ATOMIC_RELAXED,
                       __HIP_MEMORY_SCOPE_AGENT);
}

union Q2 { unsigned long long q[2]; short8 v8; };
union QF { unsigned long long q; float f[2]; };

// ---------------------------------------------------------------------------
// fp32 -> bf16 (RNE), 4 elems/thread; n % 1024 == 0
// ---------------------------------------------------------------------------
__global__ __launch_bounds__(256) void cvt_bf16(
    const float* __restrict__ src, ushort* __restrict__ dst, int n)
{
    int i = (blockIdx.x * 256 + threadIdx.x) * 4;
    if (i < n) {
        float4 v = *(const float4*)(src + i);
        ushort4 o;
        o.x = bf16_rne(v.x); o.y = bf16_rne(v.y);
        o.z = bf16_rne(v.z); o.w = bf16_rne(v.w);
        *(ushort4*)(dst + i) = o;
    }
}

// prep: h0 -> bf16, zero barrier words.  grid 256 x 256.
__global__ __launch_bounds__(256) void prep(
    const float* __restrict__ h0, ushort* __restrict__ h0b, unsigned* __restrict__ bar)
{
    int i = blockIdx.x * 256 + threadIdx.x;
    h0b[i] = bf16_rne(h0[i]);
    if (blockIdx.x == 0) { bar[threadIdx.x] = 0u; bar[threadIdx.x + 256] = 0u; }
}

// ---------------------------------------------------------------------------
// Fence-free grid barrier: per-wave vmcnt drain + relaxed-atomic arrival tree
// (8 groups x 32 blocks), spin on generation word. No L2 writeback/invalidate.
// ---------------------------------------------------------------------------
__device__ __forceinline__ void bar_sync(unsigned* bar, int blk) {
    asm volatile("s_waitcnt vmcnt(0) lgkmcnt(0)" ::: "memory");
    __syncthreads();
    if (threadIdx.x == 0) {
        unsigned* gen  = bar;
        unsigned* root = bar + 32;
        unsigned* grp  = bar + 64 + (blk >> 5) * 32;
        unsigned g = __hip_atomic_load(gen, __ATOMIC_RELAXED, __HIP_MEMORY_SCOPE_AGENT);
        if (__hip_atomic_fetch_add(grp, 1u, __ATOMIC_RELAXED, __HIP_MEMORY_SCOPE_AGENT) == 31u) {
            __hip_atomic_store(grp, 0u, __ATOMIC_RELAXED, __HIP_MEMORY_SCOPE_AGENT);
            if (__hip_atomic_fetch_add(root, 1u, __ATOMIC_RELAXED, __HIP_MEMORY_SCOPE_AGENT) == 7u) {
                __hip_atomic_store(root, 0u, __ATOMIC_RELAXED, __HIP_MEMORY_SCOPE_AGENT);
                __hip_atomic_fetch_add(gen, 1u, __ATOMIC_RELAXED, __HIP_MEMORY_SCOPE_AGENT);
            }
        }
        while (__hip_atomic_load(gen, __ATOMIC_RELAXED, __HIP_MEMORY_SCOPE_AGENT) == g)
            __builtin_amdgcn_s_sleep(2);
    }
    __syncthreads();
}

// ---------------------------------------------------------------------------
// One LSTM cell step for block (bg,ug): gates[16b x 64cols] where wave = gate
// type, col l15 = unit. h staged to LDS via coherent loads; x normal (encode)
// or coherent (decode); W normal loads (L2-resident). c in a register.
// ---------------------------------------------------------------------------
template<bool XCOH>
__device__ __forceinline__ void cell_step(
    const ushort* __restrict__ xsrc, const ushort* __restrict__ hcur,
    ushort* __restrict__ hnxt,
    const ushort* __restrict__ Wih, const ushort* __restrict__ Whh,
    ushort* hs, float* gbuf, int bg, int ug,
    float bs0, float bs1, float bs2, float bs3,
    float& c_reg, bool fin, float* __restrict__ fin_out)
{
    const int tid = threadIdx.x;
    const int wave = tid >> 6, lane = tid & 63;
    const int l15 = lane & 15, q8 = (lane >> 4) * 8, r0 = (lane >> 4) * 4;

    // stage h tile (16 rows x 1024) -> hs[row*1032+col], coherent 8B loads
    #pragma unroll
    for (int i = 0; i < 16; i++) {
        int idx = i * 256 + tid;           // qword index (4 ushorts each)
        int flat = idx * 4;
        int row = flat >> 10, col = flat & 1023;
        *(unsigned long long*)&hs[row * 1032 + col] =
            cload64(hcur + ((size_t)(bg * 16 + row) << 10) + col);
    }
    __syncthreads();

    const ushort* xp  = xsrc + ((size_t)(bg * 16 + l15) << 10) + q8;
    const ushort* wip = Wih + ((size_t)(wave * 1024 + ug * 16 + l15) << 10) + q8;
    const ushort* whp = Whh + ((size_t)(wave * 1024 + ug * 16 + l15) << 10) + q8;
    const ushort* hp  = hs + l15 * 1032 + q8;

    f32x4 acc0 = {0.f,0.f,0.f,0.f}, acc1 = {0.f,0.f,0.f,0.f};
    #pragma unroll 4
    for (int kk = 0; kk < 1024; kk += 64) {
        short8 xa0, xa1;
        if (XCOH) {
            Q2 t0; t0.q[0] = cload64(xp + kk);      t0.q[1] = cload64(xp + kk + 4);  xa0 = t0.v8;
            Q2 t1; t1.q[0] = cload64(xp + kk + 32); t1.q[1] = cload64(xp + kk + 36); xa1 = t1.v8;
        } else {
            xa0 = *(const short8*)(xp + kk);
            xa1 = *(const short8*)(xp + kk + 32);
        }
        short8 ha0 = *(const short8*)(hp + kk);
        short8 ha1 = *(const short8*)(hp + kk + 32);
        short8 wi0 = *(const short8*)(wip + kk);
        short8 wi1 = *(const short8*)(wip + kk + 32);
        short8 wh0 = *(const short8*)(whp + kk);
        short8 wh1 = *(const short8*)(whp + kk + 32);
        acc0 = MFMA16(xa0, wi0, acc0);
        acc0 = MFMA16(ha0, wh0, acc0);
        acc1 = MFMA16(xa1, wi1, acc1);
        acc1 = MFMA16(ha1, wh1, acc1);
    }
    f32x4 acc = acc0 + acc1;
    #pragma unroll
    for (int r = 0; r < 4; r++)
        gbuf[(r0 + r) * 68 + wave * 16 + l15] = acc[r];   // row=batch, col=type*16+unit
    __syncthreads();

    const int b = tid >> 4, u = tid & 15;
    float ig = gbuf[b * 68 + u]      + bs0;
    float fg = gbuf[b * 68 + 16 + u] + bs1;
    float gg = gbuf[b * 68 + 32 + u] + bs2;
    float og = gbuf[b * 68 + 48 + u] + bs3;
    float si = 1.f / (1.f + expf(-ig));
    float sf = 1.f / (1.f + expf(-fg));
    float so = 1.f / (1.f + expf(-og));
    float tg = tanhf(gg);
    float cn = sf * c_reg + si * tg;
    c_reg = cn;
    float hn = so * tanhf(cn);

    // pack 2 units -> 1 dword, coherent store
    ushort hb = bf16_rne(hn);
    unsigned hi = (unsigned)(ushort)__shfl_down((int)hb, 1);
    const size_t gidx = ((size_t)(bg * 16 + b) << 10) + ug * 16 + u;
    if ((u & 1) == 0)
        cstore32((void*)(hnxt + gidx), (unsigned)hb | (hi << 16));
    if (fin) {
        fin_out[gidx]      = hn;
        fin_out[NE + gidx] = cn;
    }
}

// ---------------------------------------------------------------------------
// Projection (blocks 0..63): block p owns out-cols [16p,16p+16).
// h read coherent (each wave reads distinct rows), W_out normal, y coherent.
// ---------------------------------------------------------------------------
__device__ __forceinline__ void proj_step(
    const ushort* __restrict__ hcur, const ushort* __restrict__ Wout,
    float* __restrict__ y, int p, float bout)
{
    const int tid = threadIdx.x;
    const int wave = tid >> 6, lane = tid & 63;
    const int l15 = lane & 15, q8 = (lane >> 4) * 8, r0 = (lane >> 4) * 4;

    const ushort* hp = hcur + ((size_t)(wave * 16 + l15) << 10) + q8;
    const ushort* wp = Wout + ((size_t)(p * 16 + l15) << 10) + q8;

    f32x4 acc0 = {0.f,0.f,0.f,0.f}, acc1 = {0.f,0.f,0.f,0.f};
    #pragma unroll 4
    for (int kk = 0; kk < 1024; kk += 64) {
        Q2 t0; t0.q[0] = cload64(hp + kk);      t0.q[1] = cload64(hp + kk + 4);
        Q2 t1; t1.q[0] = cload64(hp + kk + 32); t1.q[1] = cload64(hp + kk + 36);
        short8 w0 = *(const short8*)(wp + kk);
        short8 w1 = *(const short8*)(wp + kk + 32);
        acc0 = MFMA16(t0.v8, w0, acc0);
        acc1 = MFMA16(t1.v8, w1, acc1);
    }
    f32x4 acc = acc0 + acc1;
    #pragma unroll
    for (int r = 0; r < 4; r++) {
        union { float f; unsigned u; } cv; cv.f = acc[r] + bout;
        cstore32(y + (size_t)(wave * 16 + r0 + r) * 1024 + p * 16 + l15, cv.u);
    }
}

// ---------------------------------------------------------------------------
// Log-softmax (blocks 0..63): block b = batch row. y coherent in, fp32 out
// (normal store) + bf16 xd (coherent store).
// ---------------------------------------------------------------------------
__device__ __forceinline__ void softmax_step(
    const float* __restrict__ y, int b, float* __restrict__ outp,
    ushort* __restrict__ xd, float* red)
{
    const int tid = threadIdx.x;
    QF a, c;
    a.q = cload64(y + (size_t)b * 1024 + tid * 4);
    c.q = cload64(y + (size_t)b * 1024 + tid * 4 + 2);
    float v0 = a.f[0], v1 = a.f[1], v2 = c.f[0], v3 = c.f[1];

    red[tid] = fmaxf(fmaxf(v0, v1), fmaxf(v2, v3));
    __syncthreads();
    for (int st = 128; st > 0; st >>= 1) {
        if (tid < st) red[tid] = fmaxf(red[tid], red[tid + st]);
        __syncthreads();
    }
    float m = red[0];
    __syncthreads();
    red[tid] = expf(v0 - m) + expf(v1 - m) + expf(v2 - m) + expf(v3 - m);
    __syncthreads();
    for (int st = 128; st > 0; st >>= 1) {
        if (tid < st) red[tid] += red[tid + st];
        __syncthreads();
    }
    float lse = m + logf(red[0]);

    float4 o = make_float4(v0 - lse, v1 - lse, v2 - lse, v3 - lse);
    *(float4*)(outp + (size_t)b * 1024 + tid * 4) = o;   // normal: host-read only
    unsigned lo = (unsigned)bf16_rne(o.x) | ((unsigned)bf16_rne(o.y) << 16);
    unsigned hi = (unsigned)bf16_rne(o.z) | ((unsigned)bf16_rne(o.w) << 16);
    cstore64(xd + (size_t)b * 1024 + tid * 4,
             (unsigned long long)lo | ((unsigned long long)hi << 32));
}

// ---------------------------------------------------------------------------
// Persistent cooperative LSTM: 256 blocks (1/CU), 223 fence-free barriers.
// ---------------------------------------------------------------------------
__global__ __launch_bounds__(256, 1) void lstm_coop(
    const ushort* __restrict__ Wih, const ushort* __restrict__ Whh,
    const ushort* __restrict__ Wout, const ushort* __restrict__ Xbf,
    ushort* __restrict__ hA, ushort* __restrict__ hB, ushort* __restrict__ xd,
    float* __restrict__ y, unsigned* __restrict__ bar,
    const float* __restrict__ b_ih, const float* __restrict__ b_hh,
    const float* __restrict__ b_out, const float* __restrict__ c0,
    float* __restrict__ out)
{
    __shared__ ushort hs[16 * 1032];     // h tile, pad 8 -> 2-way-max LDS banks
    __shared__ float gbuf[16 * 68];      // gate tile / softmax scratch

    const int blk = blockIdx.x;
    const int bg = blk >> 6, ug = blk & 63;   // blk%8 = ug%8 -> W slice pinned per XCD
    const int tid = threadIdx.x;
    const int b = tid >> 4, u = tid & 15;
    const int lane = tid & 63, l15 = lane & 15;

    const int gi = ug * 16 + u;
    const float bs0 = b_ih[gi]        + b_hh[gi];
    const float bs1 = b_ih[1024 + gi] + b_hh[1024 + gi];
    const float bs2 = b_ih[2048 + gi] + b_hh[2048 + gi];
    const float bs3 = b_ih[3072 + gi] + b_hh[3072 + gi];
    float c_reg = c0[((size_t)(bg * 16 + b) << 10) + gi];
    const float bout = (blk < 64) ? b_out[blk * 16 + l15] : 0.f;

    ushort* hcur = hA;
    ushort* hnxt = hB;

    // ---- encode: 128 steps, 1 barrier each ----
    for (int t = 0; t < SEQ; t++) {
        cell_step<false>(Xbf + (size_t)t * NE, hcur, hnxt, Wih, Whh,
                         hs, gbuf, bg, ug, bs0, bs1, bs2, bs3,
                         c_reg, false, nullptr);
        bar_sync(bar, blk);
        ushort* tmp = hcur; hcur = hnxt; hnxt = tmp;
    }

    // ---- out0 ----
    if (blk < 64) proj_step(hcur, Wout, y, blk, bout);
    bar_sync(bar, blk);
    if (blk < 64) softmax_step(y, blk, out, xd, gbuf);
    bar_sync(bar, blk);

    // ---- decode: 31 steps, 3 barriers each ----
    for (int d = 1; d < TOUT; d++) {
        cell_step<true>(xd, hcur, hnxt, Wih, Whh, hs, gbuf, bg, ug,
                        bs0, bs1, bs2, bs3, c_reg,
                        d == TOUT - 1, out + (size_t)TOUT * NE);
        bar_sync(bar, blk);
        ushort* tmp = hcur; hcur = hnxt; hnxt = tmp;
        if (blk < 64) proj_step(hcur, Wout, y, blk, bout);
        bar_sync(bar, blk);
        if (blk < 64) softmax_step(y, blk, out + (size_t)d * NE, xd, gbuf);
        bar_sync(bar, blk);
    }
}

// ---------------------------------------------------------------------------
extern "C" void kernel_launch(void* const* d_in, const int* in_sizes, int n_in,
                              void* d_out, int out_size, void* d_ws, size_t ws_size,
                              hipStream_t stream)
{
    const float* input = (const float*)d_in[0];   // [128,64,1024]
    const float* h0    = (const float*)d_in[1];
    const float* c0    = (const float*)d_in[2];
    const float* W_ih  = (const float*)d_in[3];   // [4096,1024]
    const float* W_hh  = (const float*)d_in[4];
    const float* b_ih  = (const float*)d_in[5];
    const float* b_hh  = (const float*)d_in[6];
    const float* W_out = (const float*)d_in[7];   // [1024,1024]
    const float* b_out = (const float*)d_in[8];
    float* out = (float*)d_out;                   // [32,64,1024] + h + c

    char* w = (char*)d_ws;
    ushort*   Wih_bf  = (ushort*)(w + 0);          //  8,388,608 B
    ushort*   Whh_bf  = (ushort*)(w + 8388608);    //  8,388,608 B
    ushort*   Wout_bf = (ushort*)(w + 16777216);   //  2,097,152 B
    ushort*   Xbf     = (ushort*)(w + 18874368);   // 16,777,216 B
    ushort*   hA      = (ushort*)(w + 35651584);   //    131,072 B
    ushort*   hB      = (ushort*)(w + 35782656);   //    131,072 B
    ushort*   xd      = (ushort*)(w + 35913728);   //    131,072 B
    float*    y       = (float*) (w + 36044800);   //    262,144 B
    unsigned* bar     = (unsigned*)(w + 36306944); //      2,048 B

    cvt_bf16<<<dim3(4096), dim3(256), 0, stream>>>(W_ih,  Wih_bf,  NG * HD);
    cvt_bf16<<<dim3(4096), dim3(256), 0, stream>>>(W_hh,  Whh_bf,  NG * HD);
    cvt_bf16<<<dim3(1024), dim3(256), 0, stream>>>(W_out, Wout_bf, HD * HD);
    cvt_bf16<<<dim3(8192), dim3(256), 0, stream>>>(input, Xbf, SEQ * NE);
    prep<<<dim3(256), dim3(256), 0, stream>>>(h0, hA, bar);

    const ushort* a0 = Wih_bf;  const ushort* a1 = Whh_bf;
    const ushort* a2 = Wout_bf; const ushort* a3 = Xbf;
    ushort* a4 = hA; ushort* a5 = hB; ushort* a6 = xd;
    float* a7 = y; unsigned* a8 = bar;
    const float* a9 = b_ih; const float* a10 = b_hh; const float* a11 = b_out;
    const float* a12 = c0;  float* a13 = out;
    void* args[] = {&a0, &a1, &a2, &a3, &a4, &a5, &a6, &a7, &a8,
                    &a9, &a10, &a11, &a12, &a13};
    hipLaunchCooperativeKernel((const void*)lstm_coop, dim3(256), dim3(256),
                               args, 0, stream);
}